// Round 1
// baseline (286.668 us; speedup 1.0000x reference)
//
#include <hip/hip_runtime.h>
#include <hip/hip_bf16.h>

// Per-edge dot product: score[e] = sum_d h[src[e]][d] * h[dst[e]][d]
// h: [N_NODES, 128] fp32; edge_index: [2, E] int32 (JAX x64-disabled
// canonicalizes int64 -> int32; harness passes integer inputs as int*).
//
// Mapping: 32 lanes per edge. Each lane loads one float4 from the src row
// and one from the dst row (32 lanes x 16B = 512B = one full 128-float row,
// perfectly coalesced), computes a partial dot, then a 5-step shfl_xor
// reduction within the 32-lane group (offsets <32 stay inside the half-wave
// on wave64). Lane 0 of each group writes out[e].

#define D_FEAT 128
#define LANES_PER_EDGE 32
#define BLOCK 256
#define EDGES_PER_BLOCK (BLOCK / LANES_PER_EDGE)  // 8

__global__ __launch_bounds__(BLOCK) void edge_dot_kernel(
    const float* __restrict__ h,
    const int* __restrict__ edge_index,
    float* __restrict__ out,
    int E)
{
    const int group = threadIdx.x >> 5;           // 0..7 within block
    const int lane  = threadIdx.x & 31;           // 0..31 within group
    const int e     = blockIdx.x * EDGES_PER_BLOCK + group;
    if (e >= E) return;

    // All 32 lanes read the same index -> L1 broadcast, cheap.
    const int src = edge_index[e];                // row 0 of (2,E)
    const int dst = edge_index[E + e];            // row 1 of (2,E)

    const float4* __restrict__ hs =
        (const float4*)(h + (size_t)src * D_FEAT);
    const float4* __restrict__ hd =
        (const float4*)(h + (size_t)dst * D_FEAT);

    const float4 a = hs[lane];
    const float4 b = hd[lane];

    float sum = a.x * b.x + a.y * b.y + a.z * b.z + a.w * b.w;

    // Reduce across the 32-lane group. xor offsets 16,8,4,2,1 never cross
    // the 32-lane half boundary of the 64-lane wave.
    #pragma unroll
    for (int off = 16; off >= 1; off >>= 1)
        sum += __shfl_xor(sum, off);

    if (lane == 0)
        out[e] = sum;
}

extern "C" void kernel_launch(void* const* d_in, const int* in_sizes, int n_in,
                              void* d_out, int out_size, void* d_ws, size_t ws_size,
                              hipStream_t stream)
{
    const float* h         = (const float*)d_in[0];
    const int*   edge_idx  = (const int*)d_in[1];
    float*       out       = (float*)d_out;

    const int E = in_sizes[1] / 2;   // edge_index is (2, E)

    const int grid = (E + EDGES_PER_BLOCK - 1) / EDGES_PER_BLOCK;
    edge_dot_kernel<<<grid, BLOCK, 0, stream>>>(h, edge_idx, out, E);
}